// Round 19
// baseline (43.646 us; speedup 1.0000x reference)
//
#include <hip/hip_runtime.h>
#include <math.h>

#define T_LEN 200
#define SEG 100
#define NB 2048

typedef short bf8 __attribute__((ext_vector_type(8)));
typedef float f32x4 __attribute__((ext_vector_type(4)));

__device__ __forceinline__ float sigmoidf_(float x){ return 1.0f/(1.0f+__expf(-x)); }
__device__ __forceinline__ unsigned int pk_bf16(float lo, float hi){
  unsigned int r; asm("v_cvt_pk_bf16_f32 %0, %1, %2":"=v"(r):"v"(lo),"v"(hi)); return r;
}
__device__ __forceinline__ float bfu(short s){
  union{unsigned u; float f;} c; c.u = ((unsigned)(unsigned short)s)<<16; return c.f;
}
union U4B8 { uint4 u; bf8 b; };
__device__ __forceinline__ bf8 pack8(float4 x, float4 y){
  U4B8 r;
  r.u.x = pk_bf16(x.x,x.y); r.u.y = pk_bf16(x.z,x.w);
  r.u.z = pk_bf16(y.x,y.y); r.u.w = pk_bf16(y.z,y.w);
  return r.b;
}
// wk' = bf16( fbc + q ∘ fd ), elementwise over the lane's 8 k-dims
__device__ __forceinline__ bf8 combine8(bf8 fbc, bf8 fd, float4 ql, float4 qh){
  U4B8 r;
  r.u.x = pk_bf16(fmaf(ql.x, bfu(fd[0]), bfu(fbc[0])), fmaf(ql.y, bfu(fd[1]), bfu(fbc[1])));
  r.u.y = pk_bf16(fmaf(ql.z, bfu(fd[2]), bfu(fbc[2])), fmaf(ql.w, bfu(fd[3]), bfu(fbc[3])));
  r.u.z = pk_bf16(fmaf(qh.x, bfu(fd[4]), bfu(fbc[4])), fmaf(qh.y, bfu(fd[5]), bfu(fbc[5])));
  r.u.w = pk_bf16(fmaf(qh.z, bfu(fd[6]), bfu(fbc[6])), fmaf(qh.w, bfu(fd[7]), bfu(fbc[7])));
  return r.b;
}

// ws layout (float* wsf):
//   ushort fb = (ushort*)wsf : fb[0..15360) A1 frags (30), K=192:
//                              k 0..63 = k -> W1b-W1c; 64..127 = k*q -> W1d;
//                              128..191 = q -> W1a+W1c (q-term, prologue-only)
//                              fb[15360..19968) A2 frags (W2^T padded 48x96;
//                              row h=80 carries b2 via constant-1 H row)
//   wsf[10032 .. +48)      : Wf padded to 48
//   wsf[10240 .. +4096*64) : pv partials [4096][64]
//   wsf[272384 .. +4096)   : se partials [4096]
// A-frag layout (16x16x32): row = lane&15, k = ks*32 + (lane>>4)*8 + e
__global__ void prep_kernel(const float* __restrict__ W1, const float* __restrict__ W2,
                            const float* __restrict__ b2, const float* __restrict__ Wf,
                            float* __restrict__ wsf){
  unsigned short* fb = (unsigned short*)wsf;
  int i = blockIdx.x*256 + threadIdx.x;
  if (i < 15360){
    int fi = i >> 9;                  // 0..29
    int lane = (i>>3)&63, e = i&7;
    int ht = fi/6, ks = fi%6;
    int h = ht*16 + (lane&15);
    int f = ks*32 + ((lane>>4)<<3) + e;
    float val;
    if (f < 64)        val = W1[(64+f)*80+h] - W1[(128+f)*80+h];
    else if (f < 128)  val = W1[(128+f)*80+h];
    else               val = W1[(f-128)*80+h] + W1[f*80+h];
    fb[i] = (unsigned short)(pk_bf16(val,val) & 0xffffu);
  }
  if (i < 4608){
    int fi = i >> 9;                  // 0..8
    int lane = (i>>3)&63, e = i&7;
    int gt = fi/3, ks = fi%3;
    int g = gt*16 + (lane&15);
    int h = ks*32 + ((lane>>4)<<3) + e;
    float val;
    if (g < 40 && h < 80)       val = W2[h*40+g];
    else if (g < 40 && h == 80) val = b2[g];     // b2 via constant-1 H row
    else                        val = 0.f;
    fb[15360+i] = (unsigned short)(pk_bf16(val,val) & 0xffffu);
  }
  if (i < 48){
    wsf[10032 + i] = (i<40) ? Wf[i] : 0.f;
  }
}

// One wave per (b, segment-of-100-t). Fused MLP + online no-max softmax + PV
// partials. Lean LDS (13.1 KB -> 12 blocks/CU) and lean VGPR (no vnxt):
// k prefetched one pass ahead; v issued in-pass right after pack (PV wait is
// counted vmcnt, never drains k-next). Hw single-buffered (same-wave DS order).
__global__ __launch_bounds__(64, 1) void fused_partial(
    const float* __restrict__ q, const float* __restrict__ k, const float* __restrict__ v,
    const int* __restrict__ mask, const float* __restrict__ b1,
    const float* __restrict__ bf, const float* __restrict__ wsf,
    float* __restrict__ pvp, float* __restrict__ sep)
{
  __shared__ unsigned short tl[112];
  __shared__ __align__(16) unsigned int Hw[16*52]; // [16 item][52 u32]; word 40 = bf16(1.0)
  __shared__ float e_lds[16];
  __shared__ __align__(16) unsigned int w2s[9*64*4]; // 9 layer-2 frags, 9216 B

  const int lane = threadIdx.x;
  const int lg = lane>>4, lc = lane&15;
  const int bid = blockIdx.x;
  const long b = bid >> 1;
  const int tbase = (bid & 1) * SEG;

  const float* kb = k + b*(T_LEN*64);
  const float* vb = v + b*(T_LEN*64);
  const int*   mb = mask + b*T_LEN;
  const float* qb = q + b*64;
  const unsigned short* fbg = (const unsigned short*)wsf;
  const bf8* A1f = (const bf8*)fbg;
  const uint4* A2u = (const uint4*)(fbg + 15360);
  const float* wfp = wsf + 10032;

  // init H pad words (h 80..95): word 40 = bf16(1.0), rest 0 (16 rows)
  if (lane < 32){
    uint4 z = {0,0,0,0};
    if (!(lane&1)) z.x = 0x00003F80u;   // h=80 -> 1.0 (lo16), h=81 -> 0
    *(uint4*)(&Hw[(lane>>1)*52 + 40 + (lane&1)*4]) = z;
  }

  // stage layer-2 frags into LDS (once)
  #pragma unroll
  for (int i=0;i<9;++i) ((uint4*)w2s)[i*64+lane] = A2u[i*64+lane];

  // per-lane q values for this lane's 8 k-dims
  float4 qA0 = *(const float4*)(qb + lg*8);
  float4 qA1 = *(const float4*)(qb + lg*8 + 4);
  float4 qB0 = *(const float4*)(qb + 32 + lg*8);
  float4 qB1 = *(const float4*)(qb + 32 + lg*8 + 4);

  // ---- pin q-combined layer-1 frags in registers: wk[ht*2+ks], 10 frags ----
  bf8 wk[10];
  #pragma unroll
  for (int ht=0; ht<5; ++ht){
    wk[ht*2+0] = combine8(A1f[(ht*6+0)*64+lane], A1f[(ht*6+2)*64+lane], qA0, qA1);
    wk[ht*2+1] = combine8(A1f[(ht*6+1)*64+lane], A1f[(ht*6+3)*64+lane], qB0, qB1);
  }
  float wfv[12];
  #pragma unroll
  for (int gt=0; gt<3; ++gt){
    float4 wv = *(const float4*)(wfp + gt*16 + lg*4);
    wfv[gt*4+0]=wv.x; wfv[gt*4+1]=wv.y; wfv[gt*4+2]=wv.z; wfv[gt*4+3]=wv.w;
  }

  // ---- prologue: qacc[ht] = b1 + (W1a+W1c)^T q (item-independent, 10 MFMAs once) ----
  f32x4 qacc[5];
  {
    bf8 fq0 = pack8(qA0,qA1);
    bf8 fq1 = pack8(qB0,qB1);
    #pragma unroll
    for (int ht=0; ht<5; ++ht){
      float4 bv = *(const float4*)(b1 + ht*16 + lg*4);
      qacc[ht][0]=bv.x; qacc[ht][1]=bv.y; qacc[ht][2]=bv.z; qacc[ht][3]=bv.w;
      qacc[ht] = __builtin_amdgcn_mfma_f32_16x16x32_bf16(A1f[(ht*6+4)*64+lane], fq0, qacc[ht],0,0,0);
      qacc[ht] = __builtin_amdgcn_mfma_f32_16x16x32_bf16(A1f[(ht*6+5)*64+lane], fq1, qacc[ht],0,0,0);
    }
  }
  const float bf0 = bf[0];

  // ---- compaction over this segment's 100 t's (same-wave in-order DS) ----
  unsigned long long ltm = (1ull<<lane) - 1ull;
  bool f0m = (mb[tbase + lane] != 0);
  unsigned long long bal0 = __ballot(f0m);
  bool f1m = (lane < SEG-64) && (mb[tbase + 64 + lane] != 0);
  unsigned long long bal1 = __ballot(f1m);
  int c0n = (int)__popcll(bal0);
  int tot = c0n + (int)__popcll(bal1);
  if (f0m) tl[(int)__popcll(bal0 & ltm)] = (unsigned short)(tbase + lane);
  if (f1m) tl[c0n + (int)__popcll(bal1 & ltm)] = (unsigned short)(tbase + 64 + lane);

  if (tot == 0){
    pvp[(long)bid*64 + lane] = 0.f;
    if (lane == 0) sep[bid] = 0.f;
    return;
  }

  // prologue: pass-0 k loads
  int tp = tl[min(lc, tot-1)];
  const float* kr = kb + tp*64 + lg*8;
  float4 na0 = *(const float4*)(kr);
  float4 na1 = *(const float4*)(kr+4);
  float4 nb0 = *(const float4*)(kr+32);
  float4 nb1 = *(const float4*)(kr+36);

  float acc_pv0 = 0.f, acc_pv1 = 0.f;
  float se0 = 0.f, se1 = 0.f;
  for (int base = 0; base < tot; base += 16){
    const bool have_next = (base + 16 < tot);
    // consume k prefetch into bf16 fragments
    bf8 f0 = pack8(na0,na1);
    bf8 f1 = pack8(nb0,nb1);
    // issue this pass's v loads (consumed at pass end; counted vmcnt wait)
    float vcur[16];
    #pragma unroll
    for (int i=0;i<16;++i){
      int ti = tl[min(base+i, tot-1)];
      vcur[i] = vb[ti*64 + lane];
    }
    // issue next pass's k loads (newest in queue -> never drained by PV wait)
    if (have_next){
      int tn = tl[min(base+16+lc, tot-1)];
      const float* krn = kb + tn*64 + lg*8;
      na0 = *(const float4*)(krn);
      na1 = *(const float4*)(krn+4);
      nb0 = *(const float4*)(krn+32);
      nb1 = *(const float4*)(krn+36);
    }

    // layer 1
    f32x4 acc[5];
    #pragma unroll
    for (int ht=0; ht<5; ++ht) acc[ht] = qacc[ht];
    #pragma unroll
    for (int ht=0; ht<5; ++ht){
      acc[ht] = __builtin_amdgcn_mfma_f32_16x16x32_bf16(wk[ht*2+0], f0, acc[ht],0,0,0);
      acc[ht] = __builtin_amdgcn_mfma_f32_16x16x32_bf16(wk[ht*2+1], f1, acc[ht],0,0,0);
    }

    // sigmoid -> H (bf16 pairs); same-wave in-order DS, single buffer
    #pragma unroll
    for (int ht=0; ht<5; ++ht){
      #pragma unroll
      for (int rp=0; rp<2; ++rp)
        Hw[lc*52 + ht*8+lg*2+rp] = pk_bf16(sigmoidf_(acc[ht][2*rp]), sigmoidf_(acc[ht][2*rp+1]));
    }

    // layer 2: H frags + weight frags from LDS (counted lgkmcnt waits);
    // b2 arrives via the constant-1 H row (h=80)
    bf8 c0[3];
    #pragma unroll
    for (int ks=0; ks<3; ++ks) c0[ks] = *(const bf8*)(Hw + lc*52 + 16*ks + 4*lg);
    f32x4 g0[3];
    #pragma unroll
    for (int gt=0; gt<3; ++gt){ g0[gt][0]=0.f; g0[gt][1]=0.f; g0[gt][2]=0.f; g0[gt][3]=0.f; }
    #pragma unroll
    for (int gt=0; gt<3; ++gt){
      #pragma unroll
      for (int ks=0; ks<3; ++ks){
        bf8 wf2 = *(const bf8*)(w2s + ((gt*3+ks)*64+lane)*4);
        g0[gt] = __builtin_amdgcn_mfma_f32_16x16x32_bf16(wf2, c0[ks], g0[gt],0,0,0);
      }
    }
    float p0=0.f;
    #pragma unroll
    for (int gt=0; gt<3; ++gt){
      #pragma unroll
      for (int r=0;r<4;++r) p0 = fmaf(wfv[gt*4+r], sigmoidf_(g0[gt][r]), p0);
    }
    p0 += __shfl_xor(p0,16); p0 += __shfl_xor(p0,32);
    // unnormalized weight (logit bounded ~|5|: exp safe without max-sub); 0 for pad
    if (lg == 0) e_lds[lc] = (base+lc < tot) ? __expf(p0 + bf0) : 0.f;

    // online PV accumulation (waits vcur via counted vmcnt; k-next stays in flight)
    #pragma unroll
    for (int i=0;i<16;i+=2){
      float ei0 = e_lds[i];
      float ei1 = e_lds[i+1];
      se0 += ei0; se1 += ei1;
      acc_pv0 = fmaf(ei0, vcur[i],   acc_pv0);
      acc_pv1 = fmaf(ei1, vcur[i+1], acc_pv1);
    }
  }

  pvp[(long)bid*64 + lane] = acc_pv0 + acc_pv1;
  if (lane == 0) sep[bid] = se0 + se1;
}

// Combine the two segment partials per b: out = (pv0+pv1)/(se0+se1).
// Degenerate all-masked row (se==0): reference softmax is uniform -> mean(v).
__global__ __launch_bounds__(64) void combine_kernel(
    const float* __restrict__ v, const float* __restrict__ pvp,
    const float* __restrict__ sep, float* __restrict__ out)
{
  const int lane = threadIdx.x;
  const long b = blockIdx.x;
  float se = sep[2*b] + sep[2*b+1];
  float pv = pvp[(2*b)*64 + lane] + pvp[(2*b+1)*64 + lane];
  if (se > 0.f){
    out[b*64 + lane] = pv / se;
  } else {
    const float* vb = v + b*(T_LEN*64);
    float accv = 0.f;
    for (int t=0; t<T_LEN; ++t) accv += vb[t*64 + lane];
    out[b*64 + lane] = accv * (1.0f/(float)T_LEN);
  }
}

extern "C" void kernel_launch(void* const* d_in, const int* in_sizes, int n_in,
                              void* d_out, int out_size, void* d_ws, size_t ws_size,
                              hipStream_t stream) {
  const float* q    = (const float*)d_in[0];
  const float* k    = (const float*)d_in[1];
  const float* v    = (const float*)d_in[2];
  const int*   mask = (const int*)d_in[3];
  const float* W1   = (const float*)d_in[4];
  const float* b1   = (const float*)d_in[5];
  const float* W2   = (const float*)d_in[6];
  const float* b2   = (const float*)d_in[7];
  const float* Wf   = (const float*)d_in[8];
  const float* bf   = (const float*)d_in[9];
  float* out = (float*)d_out;
  float* wsf = (float*)d_ws;   // needs (10240 + 4096*64 + 4096)*4 ≈ 1.08 MB
  float* pvp = wsf + 10240;
  float* sep = wsf + 10240 + 4096*64;

  hipLaunchKernelGGL(prep_kernel, dim3(60), dim3(256), 0, stream, W1, W2, b2, Wf, wsf);
  hipLaunchKernelGGL(fused_partial, dim3(NB*2), dim3(64), 0, stream,
                     q, k, v, mask, b1, bf, wsf, pvp, sep);
  hipLaunchKernelGGL(combine_kernel, dim3(NB), dim3(64), 0, stream,
                     v, pvp, sep, out);
}

// Round 20
// 38.274 us; speedup vs baseline: 1.1403x; 1.1403x over previous
//
#include <hip/hip_runtime.h>
#include <math.h>

#define T_LEN 200

typedef short bf8 __attribute__((ext_vector_type(8)));
typedef float f32x4 __attribute__((ext_vector_type(4)));

__device__ __forceinline__ float sigmoidf_(float x){ return 1.0f/(1.0f+__expf(-x)); }
__device__ __forceinline__ unsigned int pk_bf16(float lo, float hi){
  unsigned int r; asm("v_cvt_pk_bf16_f32 %0, %1, %2":"=v"(r):"v"(lo),"v"(hi)); return r;
}
__device__ __forceinline__ float bfu(short s){
  union{unsigned u; float f;} c; c.u = ((unsigned)(unsigned short)s)<<16; return c.f;
}
union U4B8 { uint4 u; bf8 b; };
__device__ __forceinline__ bf8 pack8(float4 x, float4 y){
  U4B8 r;
  r.u.x = pk_bf16(x.x,x.y); r.u.y = pk_bf16(x.z,x.w);
  r.u.z = pk_bf16(y.x,y.y); r.u.w = pk_bf16(y.z,y.w);
  return r.b;
}
// wk' = bf16( fbc + q ∘ fd ), elementwise over the lane's 8 k-dims
__device__ __forceinline__ bf8 combine8(bf8 fbc, bf8 fd, float4 ql, float4 qh){
  U4B8 r;
  r.u.x = pk_bf16(fmaf(ql.x, bfu(fd[0]), bfu(fbc[0])), fmaf(ql.y, bfu(fd[1]), bfu(fbc[1])));
  r.u.y = pk_bf16(fmaf(ql.z, bfu(fd[2]), bfu(fbc[2])), fmaf(ql.w, bfu(fd[3]), bfu(fbc[3])));
  r.u.z = pk_bf16(fmaf(qh.x, bfu(fd[4]), bfu(fbc[4])), fmaf(qh.y, bfu(fd[5]), bfu(fbc[5])));
  r.u.w = pk_bf16(fmaf(qh.z, bfu(fd[6]), bfu(fbc[6])), fmaf(qh.w, bfu(fd[7]), bfu(fbc[7])));
  return r.b;
}

// ws layout (float* wsf):
//   ushort fb = (ushort*)wsf : fb[0..15360) A1 frags (30), K=192:
//                              k 0..63 = k -> W1b-W1c; 64..127 = k*q -> W1d;
//                              128..191 = q -> W1a+W1c (q-term, prologue-only)
//                              fb[15360..19968) A2 frags (W2^T padded 48x96;
//                              row h=80 carries b2 via constant-1 H row)
//   wsf[10032 .. +48) : Wf padded to 48
// A-frag layout (16x16x32): row = lane&15, k = ks*32 + (lane>>4)*8 + e
__global__ void prep_kernel(const float* __restrict__ W1, const float* __restrict__ W2,
                            const float* __restrict__ b2, const float* __restrict__ Wf,
                            float* __restrict__ wsf){
  unsigned short* fb = (unsigned short*)wsf;
  int i = blockIdx.x*256 + threadIdx.x;
  if (i < 15360){
    int fi = i >> 9;                  // 0..29
    int lane = (i>>3)&63, e = i&7;
    int ht = fi/6, ks = fi%6;
    int h = ht*16 + (lane&15);
    int f = ks*32 + ((lane>>4)<<3) + e;
    float val;
    if (f < 64)        val = W1[(64+f)*80+h] - W1[(128+f)*80+h];
    else if (f < 128)  val = W1[(128+f)*80+h];
    else               val = W1[(f-128)*80+h] + W1[f*80+h];
    fb[i] = (unsigned short)(pk_bf16(val,val) & 0xffffu);
  }
  if (i < 4608){
    int fi = i >> 9;                  // 0..8
    int lane = (i>>3)&63, e = i&7;
    int gt = fi/3, ks = fi%3;
    int g = gt*16 + (lane&15);
    int h = ks*32 + ((lane>>4)<<3) + e;
    float val;
    if (g < 40 && h < 80)       val = W2[h*40+g];
    else if (g < 40 && h == 80) val = b2[g];     // b2 via constant-1 H row
    else                        val = 0.f;
    fb[15360+i] = (unsigned short)(pk_bf16(val,val) & 0xffffu);
  }
  if (i < 48){
    wsf[10032 + i] = (i<40) ? Wf[i] : 0.f;
  }
}

// 4 waves per block, one b per wave (512 blocks). Per-wave: fused MLP +
// online no-max softmax + PV (r17 inner loop). w2s staged once per block;
// one barrier, then waves fully independent. v issued before the k-pack
// (counted vmcnt overlap); s_setprio around MFMA clusters.
__global__ __launch_bounds__(256, 1) void fused_kernel(
    const float* __restrict__ q, const float* __restrict__ k, const float* __restrict__ v,
    const int* __restrict__ mask, const float* __restrict__ b1,
    const float* __restrict__ bf, const float* __restrict__ wsf,
    float* __restrict__ out)
{
  __shared__ unsigned short tl_all[4][224];
  __shared__ __align__(16) unsigned int Hw_all[4][16*52]; // word 40 = bf16(1.0)
  __shared__ float e_all[4][16];
  __shared__ __align__(16) unsigned int w2s[9*64*4]; // 9 layer-2 frags, 9216 B

  const int tid  = threadIdx.x;
  const int lane = tid & 63;
  const int wid  = tid >> 6;
  const int lg = lane>>4, lc = lane&15;
  const long b = (long)blockIdx.x*4 + wid;

  const float* kb = k + b*(T_LEN*64);
  const float* vb = v + b*(T_LEN*64);
  const int*   mb = mask + b*T_LEN;
  const float* qb = q + b*64;
  const unsigned short* fbg = (const unsigned short*)wsf;
  const bf8* A1f = (const bf8*)fbg;
  const uint4* A2u = (const uint4*)(fbg + 15360);
  const float* wfp = wsf + 10032;

  unsigned short* tl = tl_all[wid];
  unsigned int*   Hw = Hw_all[wid];
  float*          e_lds = e_all[wid];

  // stage layer-2 frags into LDS cooperatively (once per block)
  for (int j = tid; j < 576; j += 256) ((uint4*)w2s)[j] = A2u[j];

  // init this wave's H pad words (h 80..95): word 40 = bf16(1.0), rest 0
  if (lane < 32){
    uint4 z = {0,0,0,0};
    if (!(lane&1)) z.x = 0x00003F80u;   // h=80 -> 1.0 (lo16), h=81 -> 0
    *(uint4*)(&Hw[(lane>>1)*52 + 40 + (lane&1)*4]) = z;
  }
  __syncthreads();   // only barrier: w2s visible; waves independent after this

  // per-lane q values for this lane's 8 k-dims
  float4 qA0 = *(const float4*)(qb + lg*8);
  float4 qA1 = *(const float4*)(qb + lg*8 + 4);
  float4 qB0 = *(const float4*)(qb + 32 + lg*8);
  float4 qB1 = *(const float4*)(qb + 32 + lg*8 + 4);

  // ---- pin q-combined layer-1 frags in registers: wk[ht*2+ks], 10 frags ----
  bf8 wk[10];
  #pragma unroll
  for (int ht=0; ht<5; ++ht){
    wk[ht*2+0] = combine8(A1f[(ht*6+0)*64+lane], A1f[(ht*6+2)*64+lane], qA0, qA1);
    wk[ht*2+1] = combine8(A1f[(ht*6+1)*64+lane], A1f[(ht*6+3)*64+lane], qB0, qB1);
  }
  float wfv[12];
  #pragma unroll
  for (int gt=0; gt<3; ++gt){
    float4 wv = *(const float4*)(wfp + gt*16 + lg*4);
    wfv[gt*4+0]=wv.x; wfv[gt*4+1]=wv.y; wfv[gt*4+2]=wv.z; wfv[gt*4+3]=wv.w;
  }

  // ---- prologue: qacc[ht] = b1 + (W1a+W1c)^T q (item-independent, 10 MFMAs once) ----
  f32x4 qacc[5];
  {
    bf8 fq0 = pack8(qA0,qA1);
    bf8 fq1 = pack8(qB0,qB1);
    #pragma unroll
    for (int ht=0; ht<5; ++ht){
      float4 bv = *(const float4*)(b1 + ht*16 + lg*4);
      qacc[ht][0]=bv.x; qacc[ht][1]=bv.y; qacc[ht][2]=bv.z; qacc[ht][3]=bv.w;
      qacc[ht] = __builtin_amdgcn_mfma_f32_16x16x32_bf16(A1f[(ht*6+4)*64+lane], fq0, qacc[ht],0,0,0);
      qacc[ht] = __builtin_amdgcn_mfma_f32_16x16x32_bf16(A1f[(ht*6+5)*64+lane], fq1, qacc[ht],0,0,0);
    }
  }
  const float bf0 = bf[0];

  // ---- compaction over this wave's 200 t's (same-wave in-order DS) ----
  int tot = 0;
  unsigned long long ltm = (1ull<<lane) - 1ull;
  #pragma unroll
  for (int c=0;c<4;++c){
    int t = c*64 + lane;
    bool f = (t < T_LEN) && (mb[t] != 0);
    unsigned long long bal = __ballot(f);
    if (f) tl[tot + (int)__popcll(bal & ltm)] = (unsigned short)t;
    tot += (int)__popcll(bal);
  }

  if (tot == 0){
    // all masked: reference softmax is uniform -> mean of v
    float accv = 0.f;
    for (int t=0; t<T_LEN; ++t) accv += vb[t*64 + lane];
    out[b*64 + lane] = accv * (1.0f/(float)T_LEN);
    return;
  }

  // prologue: pass-0 k loads
  int tp = tl[min(lc, tot-1)];
  const float* kr = kb + tp*64 + lg*8;
  float4 na0 = *(const float4*)(kr);
  float4 na1 = *(const float4*)(kr+4);
  float4 nb0 = *(const float4*)(kr+32);
  float4 nb1 = *(const float4*)(kr+36);

  float acc_pv0 = 0.f, acc_pv1 = 0.f;
  float se0 = 0.f, se1 = 0.f;
  for (int base = 0; base < tot; base += 16){
    const bool have_next = (base + 16 < tot);
    // issue this pass's v loads FIRST (no dep on k): they overlap the k wait
    float vcur[16];
    #pragma unroll
    for (int i=0;i<16;++i){
      int ti = tl[min(base+i, tot-1)];
      vcur[i] = vb[ti*64 + lane];
    }
    // consume k prefetch into bf16 fragments (counted vmcnt(16): vcur stays in flight)
    bf8 f0 = pack8(na0,na1);
    bf8 f1 = pack8(nb0,nb1);
    // issue next pass's k loads into the freed k registers
    if (have_next){
      int tn = tl[min(base+16+lc, tot-1)];
      const float* krn = kb + tn*64 + lg*8;
      na0 = *(const float4*)(krn);
      na1 = *(const float4*)(krn+4);
      nb0 = *(const float4*)(krn+32);
      nb1 = *(const float4*)(krn+36);
    }

    // layer 1
    f32x4 acc[5];
    #pragma unroll
    for (int ht=0; ht<5; ++ht) acc[ht] = qacc[ht];
    __builtin_amdgcn_s_setprio(1);
    #pragma unroll
    for (int ht=0; ht<5; ++ht){
      acc[ht] = __builtin_amdgcn_mfma_f32_16x16x32_bf16(wk[ht*2+0], f0, acc[ht],0,0,0);
      acc[ht] = __builtin_amdgcn_mfma_f32_16x16x32_bf16(wk[ht*2+1], f1, acc[ht],0,0,0);
    }
    __builtin_amdgcn_s_setprio(0);

    // sigmoid -> H (bf16 pairs); same-wave in-order DS, single buffer
    #pragma unroll
    for (int ht=0; ht<5; ++ht){
      #pragma unroll
      for (int rp=0; rp<2; ++rp)
        Hw[lc*52 + ht*8+lg*2+rp] = pk_bf16(sigmoidf_(acc[ht][2*rp]), sigmoidf_(acc[ht][2*rp+1]));
    }

    // layer 2: H frags + weight frags from LDS (counted lgkmcnt waits);
    // b2 arrives via the constant-1 H row (h=80)
    bf8 c0[3];
    #pragma unroll
    for (int ks=0; ks<3; ++ks) c0[ks] = *(const bf8*)(Hw + lc*52 + 16*ks + 4*lg);
    f32x4 g0[3];
    #pragma unroll
    for (int gt=0; gt<3; ++gt){ g0[gt][0]=0.f; g0[gt][1]=0.f; g0[gt][2]=0.f; g0[gt][3]=0.f; }
    __builtin_amdgcn_s_setprio(1);
    #pragma unroll
    for (int gt=0; gt<3; ++gt){
      #pragma unroll
      for (int ks=0; ks<3; ++ks){
        bf8 wf2 = *(const bf8*)(w2s + ((gt*3+ks)*64+lane)*4);
        g0[gt] = __builtin_amdgcn_mfma_f32_16x16x32_bf16(wf2, c0[ks], g0[gt],0,0,0);
      }
    }
    __builtin_amdgcn_s_setprio(0);
    float p0=0.f;
    #pragma unroll
    for (int gt=0; gt<3; ++gt){
      #pragma unroll
      for (int r=0;r<4;++r) p0 = fmaf(wfv[gt*4+r], sigmoidf_(g0[gt][r]), p0);
    }
    p0 += __shfl_xor(p0,16); p0 += __shfl_xor(p0,32);
    // unnormalized weight (logit bounded ~|5|: exp safe without max-sub); 0 for pad
    if (lg == 0) e_lds[lc] = (base+lc < tot) ? __expf(p0 + bf0) : 0.f;

    // online PV accumulation (waits vcur via counted vmcnt(4); k-next in flight)
    #pragma unroll
    for (int i=0;i<16;i+=2){
      float ei0 = e_lds[i];
      float ei1 = e_lds[i+1];
      se0 += ei0; se1 += ei1;
      acc_pv0 = fmaf(ei0, vcur[i],   acc_pv0);
      acc_pv1 = fmaf(ei1, vcur[i+1], acc_pv1);
    }
  }

  out[b*64 + lane] = (acc_pv0 + acc_pv1) / (se0 + se1);
}

extern "C" void kernel_launch(void* const* d_in, const int* in_sizes, int n_in,
                              void* d_out, int out_size, void* d_ws, size_t ws_size,
                              hipStream_t stream) {
  const float* q    = (const float*)d_in[0];
  const float* k    = (const float*)d_in[1];
  const float* v    = (const float*)d_in[2];
  const int*   mask = (const int*)d_in[3];
  const float* W1   = (const float*)d_in[4];
  const float* b1   = (const float*)d_in[5];
  const float* W2   = (const float*)d_in[6];
  const float* b2   = (const float*)d_in[7];
  const float* Wf   = (const float*)d_in[8];
  const float* bf   = (const float*)d_in[9];
  float* out = (float*)d_out;
  float* wsf = (float*)d_ws;   // needs 10080 floats = 40320 B

  hipLaunchKernelGGL(prep_kernel, dim3(60), dim3(256), 0, stream, W1, W2, b2, Wf, wsf);
  hipLaunchKernelGGL(fused_kernel, dim3(512), dim3(256), 0, stream,
                     q, k, v, mask, b1, bf, wsf, out);
}